// Round 9
// baseline (175.150 us; speedup 1.0000x reference)
//
#include <hip/hip_runtime.h>
#include <hip/hip_bf16.h>
#include <stdint.h>

typedef __attribute__((ext_vector_type(8))) short bf16x8;
typedef __attribute__((ext_vector_type(4))) float f32x4;
typedef __attribute__((ext_vector_type(4))) unsigned int u32x4;
typedef __attribute__((ext_vector_type(2))) unsigned int u32x2;
typedef unsigned short u16;
typedef unsigned int u32;
typedef unsigned long long u64;

#define N_NODES 8192
#define N_EDGES 1024
#define F_DIM   256
#define NMAX 128   // node degree ~ Binom(1024,.05): mean 51.2 sd 7.0, max over 8192 ~77

__device__ __forceinline__ u16 f2bf(float f) {
    union { float f; u32 u; } v; v.f = f;
    u32 u = v.u;
    u = (u + 0x7FFFu + ((u >> 16) & 1u)) >> 16;   // round-nearest-even
    return (u16)u;
}
__device__ __forceinline__ float bflo(u32 p) {
    union { u32 u; float f; } v; v.u = p << 16; return v.f;
}
__device__ __forceinline__ float bfhi(u32 p) {
    union { u32 u; float f; } v; v.u = p & 0xffff0000u; return v.f;
}

// async 16B global -> LDS (wave-uniform LDS base + lane*16; per-lane global src)
__device__ __forceinline__ void async16(const u16* g, u16* l) {
    __builtin_amdgcn_global_load_lds(
        (const __attribute__((address_space(1))) u32*)(const void*)g,
        (__attribute__((address_space(3))) u32*)(void*)l, 16, 0, 0);
}

// expand 8 mask bits -> bf16x8 of {1.0, 0.0} (elem j = bit j)
__device__ __forceinline__ bf16x8 expand8(u32 byte) {
    union { u32 u[4]; bf16x8 v; } r;
#pragma unroll
    for (int i = 0; i < 4; ++i)
        r.u[i] = (((byte >> (2 * i)) & 1u) ? 0x3F80u : 0u)
               | (((byte >> (2 * i + 1)) & 1u) ? 0x3F800000u : 0u);
    return r.v;
}

// ---------------------------------------------------------------------------
// prep — ONE pass over H (33.5 MB, the only cold HBM read). Block = 32 rows,
// 8 waves x 4 rows, loads register-staged up-front. Produces:
//   dv[n], nlist[n][.] (wave-scan compaction; spmm2w consumer),
//   Xst[f][n] = bf16(X[n][f]*rsqrt(dv[n]))  TRANSPOSED (gemm1 B-operand),
//   HbTs[seg][e] SEG-MAJOR bitmask (coalesced 4 KB row per block; gemm1 A),
//   Wb = bf16(W). Zero atomics, zero memsets in the whole pipeline.
// ---------------------------------------------------------------------------
__global__ __launch_bounds__(512) void prep(
    const float* __restrict__ H, const float* __restrict__ X,
    const float* __restrict__ W,
    float* __restrict__ dv, u16* __restrict__ nlist,
    u16* __restrict__ Xst, u32* __restrict__ HbTs, u16* __restrict__ Wb) {
    __shared__ u16 hmask[32][64];     // 4 KB
    __shared__ u16 tT[256][34];       // 17 KB transpose stage (pad 34: ~aligned u32 reads)
    const int tid = threadIdx.x;
    const int wv = tid >> 6;
    const int lane = tid & 63;
    const int blk = blockIdx.x;
    const int n0 = blk * 32 + wv * 4;

    f32x4 hv[4][4], xv[4];
#pragma unroll
    for (int r = 0; r < 4; ++r) {
        const int n = n0 + r;
#pragma unroll
        for (int q = 0; q < 4; ++q)
            hv[r][q] = *(const f32x4*)(&H[(size_t)n * N_EDGES + q * 256 + lane * 4]);
        xv[r] = *(const f32x4*)(&X[(size_t)n * F_DIM + lane * 4]);
    }

    // Wb: block blk converts W row blk (256 f32 -> bf16), one wave, ~free
    if (wv == 7) {
        const f32x4 w = *(const f32x4*)(&W[(size_t)blk * F_DIM + lane * 4]);
        u32x2 pk;
        pk[0] = (u32)f2bf(w[0]) | ((u32)f2bf(w[1]) << 16);
        pk[1] = (u32)f2bf(w[2]) | ((u32)f2bf(w[3]) << 16);
        *(u32x2*)(&Wb[(size_t)blk * F_DIM + lane * 4]) = pk;
    }

#pragma unroll
    for (int r = 0; r < 4; ++r) {
        const int n = n0 + r;
        u32 m16 = 0u;
#pragma unroll
        for (int q = 0; q < 4; ++q)
#pragma unroll
            for (int j = 0; j < 4; ++j)
                m16 |= ((hv[r][q][j] != 0.f) ? 1u : 0u) << (q * 4 + j);
        hmask[wv * 4 + r][lane] = (u16)m16;
        const u32 cl = (u32)__popc(m16);
        u32 x = cl;
#pragma unroll
        for (int d = 1; d < 64; d <<= 1) {
            const u32 t = __shfl_up(x, d, 64);
            if (lane >= d) x += t;
        }
        const u32 total = __shfl(x, 63, 64);
        u32 pos = x - cl;                 // exclusive prefix
        u16* nrow = &nlist[(size_t)n * NMAX];
        u32 m = m16;
        while (m) {
            const int bidx = __builtin_ctz(m);
            m &= m - 1;
            const int col = ((bidx >> 2) << 8) + lane * 4 + (bidx & 3);
            if (pos < NMAX) nrow[pos] = (u16)col;
            ++pos;
        }
        if (lane == 0) dv[n] = (float)total;
        const float s = rsqrtf((float)total);
        // transpose-stage scaled bf16 row into tT (column n-local = wv*4+r)
#pragma unroll
        for (int j = 0; j < 4; ++j)
            tT[lane * 4 + j][wv * 4 + r] = f2bf(xv[r][j] * s);
    }
    __syncthreads();
    // HbTs seg-major: thread t -> edges 2t, 2t+1 (contiguous 4 KB block row)
    {
        u32x2 st;
#pragma unroll
        for (int eo = 0; eo < 2; ++eo) {
            const int e = tid * 2 + eo;
            const int widx = (e & 255) >> 2;
            const int bit = ((e >> 8) << 2) + (e & 3);
            u32 w = 0u;
#pragma unroll
            for (int r = 0; r < 32; ++r)
                w |= (u32)((hmask[r][widx] >> bit) & 1u) << r;
            st[eo] = w;
        }
        *(u32x2*)(&HbTs[(size_t)blk * N_EDGES + tid * 2]) = st;
    }
    // Xst write: thread t -> (f = t&255, n-half = t>>8): 16 u16 = 32 B
    {
        const int f = tid & 255, half = tid >> 8;
        const u32* src = (const u32*)(&tT[f][half * 16]);   // byte f*68+half*32, 4-aligned
        u32x4 a, b2;
#pragma unroll
        for (int i = 0; i < 4; ++i) { a[i] = src[i]; b2[i] = src[i + 4]; }
        u16* dst = &Xst[(size_t)f * N_NODES + blk * 32 + half * 16];
        *(u32x4*)dst = a;
        *(u32x4*)(dst + 8) = b2;
    }
}

// ---------------------------------------------------------------------------
// gemm1 — Mb[e][f] = bf16( (1/de) * sum_n H[n][e] * Xsb[n][f] ) as a DENSE
// MFMA GEMM with A expanded in-register from the bitmask (replaces the random
// 215 MB gather spmm1 with streamed, coalesced B-traffic).
// 512 one-wave blocks: e-tile = bx&31 (32 edges), f-tile = bx>>5 (16 feats);
// K=8192 in 128 chunks of 64. B staged via async16 into a 4-deep ring with
// counted vmcnt(6) (loads span iterations, never drained to 0); chunks are
// XOR-swizzled at the SOURCE (m173) so ds_read_b128 frags are 2-way max.
// de = in-loop popcount (exact), folded as 1/de in the epilogue.
// ---------------------------------------------------------------------------
__global__ __launch_bounds__(64) void gemm1(
    const u16* __restrict__ Xst, const u32* __restrict__ HbTs,
    u16* __restrict__ Mb) {
    __shared__ u16 Bs[4][16][64];      // 8 KB ring, chunk-swizzled
    __shared__ float des[32];
    const int lane = threadIdx.x;
    const int e0 = (blockIdx.x & 31) * 32;
    const int f0 = (blockIdx.x >> 5) * 16;
    const int row16 = lane & 15, quad = lane >> 4;
    const int srow = lane >> 3;        // 0..7 staging row
    const int schunk = lane & 7;       // staging chunk slot
    // source addresses with chunk-XOR pre-swizzle (involution, row&7)
    const u16* gB0 = Xst + (size_t)(f0 + srow) * N_NODES + (schunk ^ (srow & 7)) * 8;
    const u16* gB1 = gB0 + (size_t)8 * N_NODES;   // rows 8..15 (same swizzle: (8+srow)&7==srow&7)

    f32x4 acc[2] = {};
    u32 cnt0 = 0, cnt1 = 0;

#define STAGE(c)  { const int _b = (c) & 3; const size_t _o = (size_t)(c) * 64; \
                    async16(gB0 + _o, (u16*)&Bs[_b][0][0]); \
                    async16(gB1 + _o, (u16*)&Bs[_b][8][0]); }
#define LOADW(c, w) { _Pragma("unroll") \
                      for (int _eh = 0; _eh < 2; ++_eh) { _Pragma("unroll") \
                      for (int _ks = 0; _ks < 2; ++_ks) \
                          w[_eh][_ks] = HbTs[(size_t)((c) * 2 + _ks) * N_EDGES + e0 + _eh * 16 + row16]; } }
#define PROCESS(w, bsel) { \
        asm volatile("s_waitcnt vmcnt(6)" ::: "memory"); \
        _Pragma("unroll") \
        for (int _ks = 0; _ks < 2; ++_ks) { \
            const bf16x8 _bf = *(const bf16x8*)(&Bs[bsel][row16][(((_ks * 4 + quad) ^ (row16 & 7)) * 8)]); \
            const u32 _b0 = (w[0][_ks] >> (quad * 8)) & 0xFFu; \
            const u32 _b1 = (w[1][_ks] >> (quad * 8)) & 0xFFu; \
            cnt0 += (u32)__popc(_b0); cnt1 += (u32)__popc(_b1); \
            acc[0] = __builtin_amdgcn_mfma_f32_16x16x32_bf16(expand8(_b0), _bf, acc[0], 0, 0, 0); \
            acc[1] = __builtin_amdgcn_mfma_f32_16x16x32_bf16(expand8(_b1), _bf, acc[1], 0, 0, 0); \
        } }

    u32 wA[2][2], wB[2][2];
    STAGE(0); STAGE(1);
    LOADW(0, wA);
    for (int it = 0; it < 128; it += 2) {
        STAGE(min(it + 2, 127));
        LOADW(min(it + 1, 127), wB);
        PROCESS(wA, (it & 3));
        STAGE(min(it + 3, 127));
        LOADW(min(it + 2, 127), wA);
        PROCESS(wB, ((it + 1) & 3));
    }
#undef STAGE
#undef LOADW
#undef PROCESS

    // de totals: sum quad-slices (lanes l, l+16, l+32, l+48 share row16)
    cnt0 += __shfl_down(cnt0, 32, 64); cnt0 += __shfl_down(cnt0, 16, 64);
    cnt1 += __shfl_down(cnt1, 32, 64); cnt1 += __shfl_down(cnt1, 16, 64);
    if (lane < 16) {
        des[lane] = 1.f / (float)cnt0;
        des[16 + lane] = 1.f / (float)cnt1;
    }
    // same-wave DS producer/consumer: in-order pipe + lgkmcnt suffice
#pragma unroll
    for (int eh = 0; eh < 2; ++eh) {
        const int col = f0 + row16;
#pragma unroll
        for (int r = 0; r < 4; ++r) {
            const int el = eh * 16 + quad * 4 + r;
            Mb[(size_t)(e0 + el) * F_DIM + col] = f2bf(acc[eh][r] * des[el]);
        }
    }
}

// ---------------------------------------------------------------------------
// spmm2w — fused node-aggregate + output GEMM. (R7 verbatim — passed twice.)
//   Y[n][:]  = sum_{e in n} Mb[e][:]            (fp32, Mb 512 KB L2-resident)
//   Yb[n][:] = bf16( rsqrt(dv[n]) * Y[n][:] )   (LDS)
//   out[n][j] = sum_f Yb[n][f]*Wb[j][f] + b[j]  (MFMA, Wb pre-converted bf16)
// 1024 blocks x 512 thr, one wave per node -> 32 waves/CU.
// ---------------------------------------------------------------------------
__global__ __launch_bounds__(512) void spmm2w(
    const u16* __restrict__ Mb, const float* __restrict__ dv,
    const u16* __restrict__ nlist, const u16* __restrict__ Wb,
    const float* __restrict__ bias, float* __restrict__ out) {
    __shared__ u16 nl[8 * NMAX];           // 2 KB
    __shared__ u16 Yb[8][264];             // 4.1 KB
    const int tid = threadIdx.x;
    const int wv = tid >> 6;               // node slot 0..7
    const int lane = tid & 63;
    const int n0 = blockIdx.x * 8;
    ((u32*)nl)[tid] = ((const u32*)&nlist[(size_t)n0 * NMAX])[tid];
    __syncthreads();
    const int half = lane >> 5, l32 = lane & 31;
    const int n = n0 + wv;
    const float dvn = dv[n];
    const int cnt = min((int)dvn, NMAX);
    const u16* lt = &nl[wv * NMAX];
    float a[8] = {};
    const int npairs = (cnt + 1) >> 1;
#pragma unroll 8
    for (int p = 0; p < npairs; ++p) {
        const int idx0 = 2 * p + half;
        const int idx = min(idx0, cnt - 1);
        const float msk = (idx0 < cnt) ? 1.f : 0.f;
        const int e = lt[idx];
        const u32x4 pk = *(const u32x4*)(&Mb[(size_t)e * F_DIM + l32 * 8]);
        a[0] = fmaf(bflo(pk[0]), msk, a[0]); a[1] = fmaf(bfhi(pk[0]), msk, a[1]);
        a[2] = fmaf(bflo(pk[1]), msk, a[2]); a[3] = fmaf(bfhi(pk[1]), msk, a[3]);
        a[4] = fmaf(bflo(pk[2]), msk, a[4]); a[5] = fmaf(bfhi(pk[2]), msk, a[5]);
        a[6] = fmaf(bflo(pk[3]), msk, a[6]); a[7] = fmaf(bfhi(pk[3]), msk, a[7]);
    }
    // cross-half combine in-register (halves hold even/odd partial sums)
#pragma unroll
    for (int k = 0; k < 8; ++k) a[k] += __shfl_xor(a[k], 32, 64);
    const float s = rsqrtf(dvn);
    if (half == 0) {                       // lanes 0..31 write the row
        u32x4 pk;
        pk[0] = (u32)f2bf(a[0] * s) | ((u32)f2bf(a[1] * s) << 16);
        pk[1] = (u32)f2bf(a[2] * s) | ((u32)f2bf(a[3] * s) << 16);
        pk[2] = (u32)f2bf(a[4] * s) | ((u32)f2bf(a[5] * s) << 16);
        pk[3] = (u32)f2bf(a[6] * s) | ((u32)f2bf(a[7] * s) << 16);
        *(u32x4*)(&Yb[wv][l32 * 8]) = pk;
    }
    __syncthreads();
    // ---- phase B: out[8 x 256] = Yb @ Wb^T + b; wave wv owns 32 cols ----
    const int row16 = lane & 15, quad = lane >> 4;
    f32x4 acc[2] = {};
    for (int ko = 0; ko < 256; ko += 32) {
        bf16x8 af = {};
        if (row16 < 8)
            af = *(const bf16x8*)(&Yb[row16][ko + quad * 8]);
#pragma unroll
        for (int tn = 0; tn < 2; ++tn) {
            const int j = wv * 32 + tn * 16 + row16;
            const bf16x8 bf = *(const bf16x8*)(&Wb[(size_t)j * F_DIM + ko + quad * 8]);
            acc[tn] = __builtin_amdgcn_mfma_f32_16x16x32_bf16(af, bf, acc[tn], 0, 0, 0);
        }
    }
#pragma unroll
    for (int tn = 0; tn < 2; ++tn) {
        const int col = wv * 32 + tn * 16 + row16;
        const float bc = bias[col];
#pragma unroll
        for (int r2 = 0; r2 < 4; ++r2) {
            const int row = quad * 4 + r2;
            if (row < 8)
                out[(size_t)(n0 + row) * F_DIM + col] = acc[tn][r2] + bc;
        }
    }
}

// ---------------------------------------------------------------------------
extern "C" void kernel_launch(void* const* d_in, const int* in_sizes, int n_in,
                              void* d_out, int out_size, void* d_ws, size_t ws_size,
                              hipStream_t stream) {
    (void)in_sizes; (void)n_in; (void)out_size; (void)ws_size;
    const float* X = (const float*)d_in[0];   // [8192 x 256]
    const float* H = (const float*)d_in[1];   // [8192 x 1024]
    const float* W = (const float*)d_in[2];   // [256 x 256]
    const float* b = (const float*)d_in[3];   // [256]
    float* out = (float*)d_out;               // [8192 x 256] fp32

    char* ws = (char*)d_ws;
    float* dv    = (float*)(ws);               // 32 KB  [8192]
    u32*   HbTs  = (u32*)(ws + 0x10000);       // 1 MB   [256 seg][1024 e] u32
    u16*   nlist = (u16*)(ws + 0x110000);      // 2 MB   [8192][128]
    u16*   Xst   = (u16*)(ws + 0x310000);      // 4 MB   [256 f][8192 n] bf16
    u16*   Mb    = (u16*)(ws + 0x710000);      // 512 KB [1024][256] bf16 (has /de)
    u16*   Wb    = (u16*)(ws + 0x790000);      // 128 KB [256][256] bf16

    prep<<<256, 512, 0, stream>>>(H, X, W, dv, nlist, Xst, HbTs, Wb);
    gemm1<<<512, 64, 0, stream>>>(Xst, HbTs, Mb);
    spmm2w<<<N_NODES / 8, 512, 0, stream>>>(Mb, dv, nlist, Wb, b, out);
}

// Round 10
// 142.506 us; speedup vs baseline: 1.2291x; 1.2291x over previous
//
#include <hip/hip_runtime.h>
#include <hip/hip_bf16.h>
#include <stdint.h>

typedef __attribute__((ext_vector_type(8))) short bf16x8;
typedef __attribute__((ext_vector_type(4))) float f32x4;
typedef __attribute__((ext_vector_type(4))) unsigned int u32x4;
typedef __attribute__((ext_vector_type(2))) unsigned int u32x2;
typedef unsigned short u16;
typedef unsigned int u32;
typedef unsigned long long u64;

#define N_NODES 8192
#define N_EDGES 1024
#define F_DIM   256
#define NMAX 128   // node degree ~ Binom(1024,.05): mean 51.2 sd 7.0, max over 8192 ~77

__device__ __forceinline__ u16 f2bf(float f) {
    union { float f; u32 u; } v; v.f = f;
    u32 u = v.u;
    u = (u + 0x7FFFu + ((u >> 16) & 1u)) >> 16;   // round-nearest-even
    return (u16)u;
}
__device__ __forceinline__ float bflo(u32 p) {
    union { u32 u; float f; } v; v.u = p << 16; return v.f;
}
__device__ __forceinline__ float bfhi(u32 p) {
    union { u32 u; float f; } v; v.u = p & 0xffff0000u; return v.f;
}

// expand 8 mask bits -> bf16x8 of {1.0, 0.0} (elem j = bit j)
__device__ __forceinline__ bf16x8 expand8(u32 byte) {
    union { u32 u[4]; bf16x8 v; } r;
#pragma unroll
    for (int i = 0; i < 4; ++i)
        r.u[i] = (((byte >> (2 * i)) & 1u) ? 0x3F80u : 0u)
               | (((byte >> (2 * i + 1)) & 1u) ? 0x3F800000u : 0u);
    return r.v;
}

// ---------------------------------------------------------------------------
// prep — ONE pass over H (33.5 MB, the only cold HBM read). Block = 32 rows,
// 8 waves x 4 rows, loads register-staged up-front. Produces:
//   dv[n], nlist[n][.] (wave-scan compaction; spmm2w consumer),
//   Xst[f][n] = bf16(X[n][f]*rsqrt(dv[n]))  TRANSPOSED (gemm1 B-operand),
//   HbTs[seg][e] SEG-MAJOR bitmask (coalesced 4 KB row per block; gemm1 A),
//   Wb = bf16(W). Zero atomics, zero memsets. (R9 verbatim — passed.)
// ---------------------------------------------------------------------------
__global__ __launch_bounds__(512) void prep(
    const float* __restrict__ H, const float* __restrict__ X,
    const float* __restrict__ W,
    float* __restrict__ dv, u16* __restrict__ nlist,
    u16* __restrict__ Xst, u32* __restrict__ HbTs, u16* __restrict__ Wb) {
    __shared__ u16 hmask[32][64];     // 4 KB
    __shared__ u16 tT[256][34];       // 17 KB transpose stage
    const int tid = threadIdx.x;
    const int wv = tid >> 6;
    const int lane = tid & 63;
    const int blk = blockIdx.x;
    const int n0 = blk * 32 + wv * 4;

    f32x4 hv[4][4], xv[4];
#pragma unroll
    for (int r = 0; r < 4; ++r) {
        const int n = n0 + r;
#pragma unroll
        for (int q = 0; q < 4; ++q)
            hv[r][q] = *(const f32x4*)(&H[(size_t)n * N_EDGES + q * 256 + lane * 4]);
        xv[r] = *(const f32x4*)(&X[(size_t)n * F_DIM + lane * 4]);
    }

    // Wb: block blk converts W row blk (256 f32 -> bf16), one wave, ~free
    if (wv == 7) {
        const f32x4 w = *(const f32x4*)(&W[(size_t)blk * F_DIM + lane * 4]);
        u32x2 pk;
        pk[0] = (u32)f2bf(w[0]) | ((u32)f2bf(w[1]) << 16);
        pk[1] = (u32)f2bf(w[2]) | ((u32)f2bf(w[3]) << 16);
        *(u32x2*)(&Wb[(size_t)blk * F_DIM + lane * 4]) = pk;
    }

#pragma unroll
    for (int r = 0; r < 4; ++r) {
        const int n = n0 + r;
        u32 m16 = 0u;
#pragma unroll
        for (int q = 0; q < 4; ++q)
#pragma unroll
            for (int j = 0; j < 4; ++j)
                m16 |= ((hv[r][q][j] != 0.f) ? 1u : 0u) << (q * 4 + j);
        hmask[wv * 4 + r][lane] = (u16)m16;
        const u32 cl = (u32)__popc(m16);
        u32 x = cl;
#pragma unroll
        for (int d = 1; d < 64; d <<= 1) {
            const u32 t = __shfl_up(x, d, 64);
            if (lane >= d) x += t;
        }
        const u32 total = __shfl(x, 63, 64);
        u32 pos = x - cl;                 // exclusive prefix
        u16* nrow = &nlist[(size_t)n * NMAX];
        u32 m = m16;
        while (m) {
            const int bidx = __builtin_ctz(m);
            m &= m - 1;
            const int col = ((bidx >> 2) << 8) + lane * 4 + (bidx & 3);
            if (pos < NMAX) nrow[pos] = (u16)col;
            ++pos;
        }
        if (lane == 0) dv[n] = (float)total;
        const float s = rsqrtf((float)total);
#pragma unroll
        for (int j = 0; j < 4; ++j)
            tT[lane * 4 + j][wv * 4 + r] = f2bf(xv[r][j] * s);
    }
    __syncthreads();
    // HbTs seg-major: thread t -> edges 2t, 2t+1 (contiguous 4 KB block row)
    {
        u32x2 st;
#pragma unroll
        for (int eo = 0; eo < 2; ++eo) {
            const int e = tid * 2 + eo;
            const int widx = (e & 255) >> 2;
            const int bit = ((e >> 8) << 2) + (e & 3);
            u32 w = 0u;
#pragma unroll
            for (int r = 0; r < 32; ++r)
                w |= (u32)((hmask[r][widx] >> bit) & 1u) << r;
            st[eo] = w;
        }
        *(u32x2*)(&HbTs[(size_t)blk * N_EDGES + tid * 2]) = st;
    }
    // Xst write: thread t -> (f = t&255, n-half = t>>8): 16 u16 = 32 B
    {
        const int f = tid & 255, half = tid >> 8;
        const u32* src = (const u32*)(&tT[f][half * 16]);
        u32x4 a, b2;
#pragma unroll
        for (int i = 0; i < 4; ++i) { a[i] = src[i]; b2[i] = src[i + 4]; }
        u16* dst = &Xst[(size_t)f * N_NODES + blk * 32 + half * 16];
        *(u32x4*)dst = a;
        *(u32x4*)(dst + 8) = b2;
    }
}

// ---------------------------------------------------------------------------
// gemm1 v2 — Mb[e][f] = bf16( (1/de) * sum_n H[n][e]*Xs[n][f] ) as a dense
// MFMA GEMM, A expanded in-register from the bitmask. R9 post-mortem fixes:
//   * 4-wave blocks, K-SPLIT per wave (wv owns nodes [wv*2048, +2048)):
//     grid 512 x 256 thr -> 8 waves/CU (R9 had 2: Occupancy 5%).
//   * NO LDS staging / manual vmcnt: B-fragments load straight to registers
//     (lane reads Xst[(f0+row16)*8192 + k + quad*8], 16 B) in double-buffered
//     4-chunk batches -> ~24 independent loads in flight, compiler-scheduled.
//   * cross-wave acc + popcount(de) reduce via LDS; /de in epilogue.
// Fragment/epilogue mapping identical to R9 (numerically verified).
// ---------------------------------------------------------------------------
__global__ __launch_bounds__(256) void gemm1(
    const u16* __restrict__ Xst, const u32* __restrict__ HbTs,
    u16* __restrict__ Mb) {
    __shared__ float red[4][2][64][4];   // 8 KB  per-wave f32x4 partials
    __shared__ float cnts[4][2][16];     // 384 B per-wave de partials
    const int tid = threadIdx.x;
    const int wv = tid >> 6, lane = tid & 63;
    const int e0 = (blockIdx.x & 31) * 32;
    const int f0 = (blockIdx.x >> 5) * 16;
    const int row16 = lane & 15, quad = lane >> 4;
    const int C0 = wv * 32;              // first 64-node chunk of this wave
    const u16* bp = Xst + (size_t)(f0 + row16) * N_NODES + quad * 8;
    const u32* wp = HbTs + e0 + row16;

    f32x4 acc[2] = {};
    u32 cnt0 = 0, cnt1 = 0;

    auto LOAD = [&](u32x4 (&B)[4][2], u32 (&Wd)[4][2][2], int base) {
#pragma unroll
        for (int c = 0; c < 4; ++c) {
            const size_t k0 = (size_t)(C0 + base + c) * 64;
#pragma unroll
            for (int ks = 0; ks < 2; ++ks)
                B[c][ks] = *(const u32x4*)(bp + k0 + ks * 32);
            const size_t s0 = (size_t)(C0 + base + c) * 2 * N_EDGES;
#pragma unroll
            for (int ks = 0; ks < 2; ++ks)
#pragma unroll
                for (int eh = 0; eh < 2; ++eh)
                    Wd[c][ks][eh] = wp[s0 + (size_t)ks * N_EDGES + eh * 16];
        }
    };
    auto COMP = [&](u32x4 (&B)[4][2], u32 (&Wd)[4][2][2]) {
#pragma unroll
        for (int c = 0; c < 4; ++c)
#pragma unroll
            for (int ks = 0; ks < 2; ++ks) {
                union { u32x4 u; bf16x8 v; } bu; bu.u = B[c][ks];
                const u32 b0 = (Wd[c][ks][0] >> (quad * 8)) & 0xFFu;
                const u32 b1 = (Wd[c][ks][1] >> (quad * 8)) & 0xFFu;
                cnt0 += (u32)__popc(b0); cnt1 += (u32)__popc(b1);
                acc[0] = __builtin_amdgcn_mfma_f32_16x16x32_bf16(expand8(b0), bu.v, acc[0], 0, 0, 0);
                acc[1] = __builtin_amdgcn_mfma_f32_16x16x32_bf16(expand8(b1), bu.v, acc[1], 0, 0, 0);
            }
    };

    u32x4 Ba[4][2], Bb[4][2];
    u32   Wa[4][2][2], Wc[4][2][2];
    LOAD(Ba, Wa, 0);
    for (int b = 0; b < 32; b += 8) {
        LOAD(Bb, Wc, b + 4);
        COMP(Ba, Wa);
        LOAD(Ba, Wa, min(b + 8, 28));    // last iter: harmless reload of 28
        COMP(Bb, Wc);
    }

    // de partials: sum quad-slices (lanes l, l+16, l+32, l+48 share edge row16)
    cnt0 += __shfl_down(cnt0, 32, 64); cnt0 += __shfl_down(cnt0, 16, 64);
    cnt1 += __shfl_down(cnt1, 32, 64); cnt1 += __shfl_down(cnt1, 16, 64);
    if (lane < 16) {
        cnts[wv][0][lane] = (float)cnt0;
        cnts[wv][1][lane] = (float)cnt1;
    }
#pragma unroll
    for (int eh = 0; eh < 2; ++eh)
        *(f32x4*)(&red[wv][eh][lane][0]) = acc[eh];
    __syncthreads();
    if (wv < 2) {                        // 128 threads: eh = wv
        const int eh = wv;
        f32x4 s = {};
#pragma unroll
        for (int w = 0; w < 4; ++w) {
            const f32x4 v = *(const f32x4*)(&red[w][eh][lane][0]);
            s[0] += v[0]; s[1] += v[1]; s[2] += v[2]; s[3] += v[3];
        }
#pragma unroll
        for (int r = 0; r < 4; ++r) {
            const int ei = quad * 4 + r;                 // edge index within 16
            const float de = cnts[0][eh][ei] + cnts[1][eh][ei] +
                             cnts[2][eh][ei] + cnts[3][eh][ei];
            const int el = eh * 16 + ei;
            Mb[(size_t)(e0 + el) * F_DIM + f0 + row16] = f2bf(s[r] / de);
        }
    }
}

// ---------------------------------------------------------------------------
// spmm2w — fused node-aggregate + output GEMM. (R7 verbatim — passed 3x.)
//   Y[n][:]  = sum_{e in n} Mb[e][:]            (fp32, Mb 512 KB L2-resident)
//   Yb[n][:] = bf16( rsqrt(dv[n]) * Y[n][:] )   (LDS)
//   out[n][j] = sum_f Yb[n][f]*Wb[j][f] + b[j]  (MFMA, Wb pre-converted bf16)
// 1024 blocks x 512 thr, one wave per node -> 32 waves/CU.
// ---------------------------------------------------------------------------
__global__ __launch_bounds__(512) void spmm2w(
    const u16* __restrict__ Mb, const float* __restrict__ dv,
    const u16* __restrict__ nlist, const u16* __restrict__ Wb,
    const float* __restrict__ bias, float* __restrict__ out) {
    __shared__ u16 nl[8 * NMAX];           // 2 KB
    __shared__ u16 Yb[8][264];             // 4.1 KB
    const int tid = threadIdx.x;
    const int wv = tid >> 6;               // node slot 0..7
    const int lane = tid & 63;
    const int n0 = blockIdx.x * 8;
    ((u32*)nl)[tid] = ((const u32*)&nlist[(size_t)n0 * NMAX])[tid];
    __syncthreads();
    const int half = lane >> 5, l32 = lane & 31;
    const int n = n0 + wv;
    const float dvn = dv[n];
    const int cnt = min((int)dvn, NMAX);
    const u16* lt = &nl[wv * NMAX];
    float a[8] = {};
    const int npairs = (cnt + 1) >> 1;
#pragma unroll 8
    for (int p = 0; p < npairs; ++p) {
        const int idx0 = 2 * p + half;
        const int idx = min(idx0, cnt - 1);
        const float msk = (idx0 < cnt) ? 1.f : 0.f;
        const int e = lt[idx];
        const u32x4 pk = *(const u32x4*)(&Mb[(size_t)e * F_DIM + l32 * 8]);
        a[0] = fmaf(bflo(pk[0]), msk, a[0]); a[1] = fmaf(bfhi(pk[0]), msk, a[1]);
        a[2] = fmaf(bflo(pk[1]), msk, a[2]); a[3] = fmaf(bfhi(pk[1]), msk, a[3]);
        a[4] = fmaf(bflo(pk[2]), msk, a[4]); a[5] = fmaf(bfhi(pk[2]), msk, a[5]);
        a[6] = fmaf(bflo(pk[3]), msk, a[6]); a[7] = fmaf(bfhi(pk[3]), msk, a[7]);
    }
#pragma unroll
    for (int k = 0; k < 8; ++k) a[k] += __shfl_xor(a[k], 32, 64);
    const float s = rsqrtf(dvn);
    if (half == 0) {                       // lanes 0..31 write the row
        u32x4 pk;
        pk[0] = (u32)f2bf(a[0] * s) | ((u32)f2bf(a[1] * s) << 16);
        pk[1] = (u32)f2bf(a[2] * s) | ((u32)f2bf(a[3] * s) << 16);
        pk[2] = (u32)f2bf(a[4] * s) | ((u32)f2bf(a[5] * s) << 16);
        pk[3] = (u32)f2bf(a[6] * s) | ((u32)f2bf(a[7] * s) << 16);
        *(u32x4*)(&Yb[wv][l32 * 8]) = pk;
    }
    __syncthreads();
    // ---- phase B: out[8 x 256] = Yb @ Wb^T + b; wave wv owns 32 cols ----
    const int row16 = lane & 15, quad = lane >> 4;
    f32x4 acc[2] = {};
    for (int ko = 0; ko < 256; ko += 32) {
        bf16x8 af = {};
        if (row16 < 8)
            af = *(const bf16x8*)(&Yb[row16][ko + quad * 8]);
#pragma unroll
        for (int tn = 0; tn < 2; ++tn) {
            const int j = wv * 32 + tn * 16 + row16;
            const bf16x8 bf = *(const bf16x8*)(&Wb[(size_t)j * F_DIM + ko + quad * 8]);
            acc[tn] = __builtin_amdgcn_mfma_f32_16x16x32_bf16(af, bf, acc[tn], 0, 0, 0);
        }
    }
#pragma unroll
    for (int tn = 0; tn < 2; ++tn) {
        const int col = wv * 32 + tn * 16 + row16;
        const float bc = bias[col];
#pragma unroll
        for (int r2 = 0; r2 < 4; ++r2) {
            const int row = quad * 4 + r2;
            if (row < 8)
                out[(size_t)(n0 + row) * F_DIM + col] = acc[tn][r2] + bc;
        }
    }
}

// ---------------------------------------------------------------------------
extern "C" void kernel_launch(void* const* d_in, const int* in_sizes, int n_in,
                              void* d_out, int out_size, void* d_ws, size_t ws_size,
                              hipStream_t stream) {
    (void)in_sizes; (void)n_in; (void)out_size; (void)ws_size;
    const float* X = (const float*)d_in[0];   // [8192 x 256]
    const float* H = (const float*)d_in[1];   // [8192 x 1024]
    const float* W = (const float*)d_in[2];   // [256 x 256]
    const float* b = (const float*)d_in[3];   // [256]
    float* out = (float*)d_out;               // [8192 x 256] fp32

    char* ws = (char*)d_ws;
    float* dv    = (float*)(ws);               // 32 KB  [8192]
    u32*   HbTs  = (u32*)(ws + 0x10000);       // 1 MB   [256 seg][1024 e] u32
    u16*   nlist = (u16*)(ws + 0x110000);      // 2 MB   [8192][128]
    u16*   Xst   = (u16*)(ws + 0x310000);      // 4 MB   [256 f][8192 n] bf16
    u16*   Mb    = (u16*)(ws + 0x710000);      // 512 KB [1024][256] bf16 (has /de)
    u16*   Wb    = (u16*)(ws + 0x790000);      // 128 KB [256][256] bf16

    prep<<<256, 512, 0, stream>>>(H, X, W, dv, nlist, Xst, HbTs, Wb);
    gemm1<<<512, 256, 0, stream>>>(Xst, HbTs, Mb);
    spmm2w<<<N_NODES / 8, 512, 0, stream>>>(Mb, dv, nlist, Wb, b, out);
}

// Round 11
// 138.437 us; speedup vs baseline: 1.2652x; 1.0294x over previous
//
#include <hip/hip_runtime.h>
#include <hip/hip_bf16.h>
#include <stdint.h>

typedef __attribute__((ext_vector_type(8))) short bf16x8;
typedef __attribute__((ext_vector_type(4))) float f32x4;
typedef __attribute__((ext_vector_type(4))) unsigned int u32x4;
typedef __attribute__((ext_vector_type(2))) unsigned int u32x2;
typedef unsigned short u16;
typedef unsigned int u32;
typedef unsigned char u8;
typedef unsigned long long u64;

#define N_NODES 8192
#define N_EDGES 1024
#define F_DIM   256
#define NMAX 128   // node degree ~ Binom(1024,.05): mean 51.2 sd 7.0, max over 8192 ~77

__device__ __forceinline__ u16 f2bf(float f) {
    union { float f; u32 u; } v; v.f = f;
    u32 u = v.u;
    u = (u + 0x7FFFu + ((u >> 16) & 1u)) >> 16;   // round-nearest-even
    return (u16)u;
}
__device__ __forceinline__ float bflo(u32 p) {
    union { u32 u; float f; } v; v.u = p << 16; return v.f;
}
__device__ __forceinline__ float bfhi(u32 p) {
    union { u32 u; float f; } v; v.u = p & 0xffff0000u; return v.f;
}

// async 16B global -> LDS (wave-uniform LDS base + lane*16; per-lane global src)
__device__ __forceinline__ void async16(const u16* g, u16* l) {
    __builtin_amdgcn_global_load_lds(
        (const __attribute__((address_space(1))) u32*)(const void*)g,
        (__attribute__((address_space(3))) u32*)(void*)l, 16, 0, 0);
}

// expand 8 mask bits -> bf16x8 of {1.0, 0.0} (elem j = bit j)
__device__ __forceinline__ bf16x8 expand8(u32 byte) {
    union { u32 u[4]; bf16x8 v; } r;
#pragma unroll
    for (int i = 0; i < 4; ++i)
        r.u[i] = (((byte >> (2 * i)) & 1u) ? 0x3F80u : 0u)
               | (((byte >> (2 * i + 1)) & 1u) ? 0x3F800000u : 0u);
    return r.v;
}

// ---------------------------------------------------------------------------
// prep — ONE pass over H (33.5 MB, the only cold HBM read). Block = 32 rows,
// 8 waves x 4 rows, loads register-staged up-front. Produces:
//   dv[n], nlist[n][.] (wave-scan compaction; spmm2w consumer),
//   Xst[f][n] = bf16(X[n][f]*rsqrt(dv[n]))  TRANSPOSED (gemm1 B-operand),
//   HbTs[seg][e] SEG-MAJOR bitmask (coalesced 4 KB row per block; gemm1 A),
//   Wb = bf16(W). Zero atomics, zero memsets. (R10 verbatim — passed.)
// ---------------------------------------------------------------------------
__global__ __launch_bounds__(512) void prep(
    const float* __restrict__ H, const float* __restrict__ X,
    const float* __restrict__ W,
    float* __restrict__ dv, u16* __restrict__ nlist,
    u16* __restrict__ Xst, u32* __restrict__ HbTs, u16* __restrict__ Wb) {
    __shared__ u16 hmask[32][64];     // 4 KB
    __shared__ u16 tT[256][34];       // 17 KB transpose stage
    const int tid = threadIdx.x;
    const int wv = tid >> 6;
    const int lane = tid & 63;
    const int blk = blockIdx.x;
    const int n0 = blk * 32 + wv * 4;

    f32x4 hv[4][4], xv[4];
#pragma unroll
    for (int r = 0; r < 4; ++r) {
        const int n = n0 + r;
#pragma unroll
        for (int q = 0; q < 4; ++q)
            hv[r][q] = *(const f32x4*)(&H[(size_t)n * N_EDGES + q * 256 + lane * 4]);
        xv[r] = *(const f32x4*)(&X[(size_t)n * F_DIM + lane * 4]);
    }

    // Wb: block blk converts W row blk (256 f32 -> bf16), one wave, ~free
    if (wv == 7) {
        const f32x4 w = *(const f32x4*)(&W[(size_t)blk * F_DIM + lane * 4]);
        u32x2 pk;
        pk[0] = (u32)f2bf(w[0]) | ((u32)f2bf(w[1]) << 16);
        pk[1] = (u32)f2bf(w[2]) | ((u32)f2bf(w[3]) << 16);
        *(u32x2*)(&Wb[(size_t)blk * F_DIM + lane * 4]) = pk;
    }

#pragma unroll
    for (int r = 0; r < 4; ++r) {
        const int n = n0 + r;
        u32 m16 = 0u;
#pragma unroll
        for (int q = 0; q < 4; ++q)
#pragma unroll
            for (int j = 0; j < 4; ++j)
                m16 |= ((hv[r][q][j] != 0.f) ? 1u : 0u) << (q * 4 + j);
        hmask[wv * 4 + r][lane] = (u16)m16;
        const u32 cl = (u32)__popc(m16);
        u32 x = cl;
#pragma unroll
        for (int d = 1; d < 64; d <<= 1) {
            const u32 t = __shfl_up(x, d, 64);
            if (lane >= d) x += t;
        }
        const u32 total = __shfl(x, 63, 64);
        u32 pos = x - cl;                 // exclusive prefix
        u16* nrow = &nlist[(size_t)n * NMAX];
        u32 m = m16;
        while (m) {
            const int bidx = __builtin_ctz(m);
            m &= m - 1;
            const int col = ((bidx >> 2) << 8) + lane * 4 + (bidx & 3);
            if (pos < NMAX) nrow[pos] = (u16)col;
            ++pos;
        }
        if (lane == 0) dv[n] = (float)total;
        const float s = rsqrtf((float)total);
#pragma unroll
        for (int j = 0; j < 4; ++j)
            tT[lane * 4 + j][wv * 4 + r] = f2bf(xv[r][j] * s);
    }
    __syncthreads();
    // HbTs seg-major: thread t -> edges 2t, 2t+1 (contiguous 4 KB block row)
    {
        u32x2 st;
#pragma unroll
        for (int eo = 0; eo < 2; ++eo) {
            const int e = tid * 2 + eo;
            const int widx = (e & 255) >> 2;
            const int bit = ((e >> 8) << 2) + (e & 3);
            u32 w = 0u;
#pragma unroll
            for (int r = 0; r < 32; ++r)
                w |= (u32)((hmask[r][widx] >> bit) & 1u) << r;
            st[eo] = w;
        }
        *(u32x2*)(&HbTs[(size_t)blk * N_EDGES + tid * 2]) = st;
    }
    // Xst write: thread t -> (f = t&255, n-half = t>>8): 16 u16 = 32 B
    {
        const int f = tid & 255, half = tid >> 8;
        const u32* src = (const u32*)(&tT[f][half * 16]);
        u32x4 a, b2;
#pragma unroll
        for (int i = 0; i < 4; ++i) { a[i] = src[i]; b2[i] = src[i + 4]; }
        u16* dst = &Xst[(size_t)f * N_NODES + blk * 32 + half * 16];
        *(u32x4*)dst = a;
        *(u32x4*)(dst + 8) = b2;
    }
}

// ---------------------------------------------------------------------------
// gemm1 v3 — Mb[e][f] = bf16( (1/de) * sum_n H[n][e]*Xs[n][f] ), dense MFMA
// with A expanded in-register from the bitmask. R10 post-mortem fixes:
//   * 256 blocks x 8 waves (32e x 32f tile, in-block K-split 8 x 1024):
//     LDS 65 KB -> 2 blocks/CU = 16 waves/CU (R10 had 8, R9 had 2).
//   * wave-PRIVATE global_load_lds double-buffer, ZERO barriers in K-loop.
//     Staging lane-order == fragment lane-order: each lane ds_reads its OWN
//     16 B at lane*16 — linear, conflict-free, no swizzle needed.
//   * counted vmcnt(4) (all-but-newest-4): exactly 4 async16 issue between
//     waits, so the consumed buffer is guaranteed landed even if hipcc
//     hoists the w-loads (hoists only add NEWER ops). sched_barrier fences.
//   * f-group (32 feats) == bid%8 == XCD id: each XCD's 32 blocks share one
//     512 KB B-panel -> resident in that XCD's private L2.
// Epilogue: 8-wave reduce overlaid on the dead staging LDS (stride-17 pad),
// de = exact in-loop popcount, /de folded. No atomics, no memsets.
// ---------------------------------------------------------------------------
__global__ __launch_bounds__(512) void gemm1(
    const u16* __restrict__ Xst, const u32* __restrict__ HbTs,
    u16* __restrict__ Mb) {
    __shared__ __align__(16) u8 smem[65536];   // [8 wv][2 buf][4 KB] ring; reduce overlay
    __shared__ float cnts[8][2][16];
    const int tid = threadIdx.x;
    const int wv = tid >> 6, lane = tid & 63;
    const int f0 = ((int)blockIdx.x & 7) * 32;   // f-group == XCD
    const int e0 = ((int)blockIdx.x >> 3) * 32;
    const int row16 = lane & 15, quad = lane >> 4;
    const int srow = lane & 15, schunk = lane >> 4;
    u16* myBs = (u16*)(smem + wv * 8192);        // u16 units below
    const int kbase = wv * 1024;                 // wave's private K-range

    f32x4 acc[2][2] = {};
    u32 cnt0 = 0, cnt1 = 0;
    u32 wA[2][2], wB[2][2];

    auto STAGE = [&](int it, int buf) {
        __builtin_amdgcn_sched_barrier(0);
        const int k0 = kbase + it * 64;
#pragma unroll
        for (int tn = 0; tn < 2; ++tn)
#pragma unroll
            for (int ks = 0; ks < 2; ++ks)
                async16(Xst + (size_t)(f0 + tn * 16 + srow) * N_NODES + k0 + ks * 32 + schunk * 8,
                        myBs + buf * 2048 + (tn * 2 + ks) * 512);
    };
    auto LOADW = [&](int it, u32 (&w)[2][2]) {
        const int k0 = kbase + it * 64;
#pragma unroll
        for (int tm = 0; tm < 2; ++tm)
#pragma unroll
            for (int ks = 0; ks < 2; ++ks)
                w[tm][ks] = HbTs[(size_t)((k0 >> 5) + ks) * N_EDGES + e0 + tm * 16 + row16];
    };
    auto COMPUTE = [&](int buf, u32 (&w)[2][2]) {
        asm volatile("s_waitcnt vmcnt(4)" ::: "memory");
        __builtin_amdgcn_sched_barrier(0);
#pragma unroll
        for (int ks = 0; ks < 2; ++ks) {
            bf16x8 bfr[2];
#pragma unroll
            for (int tn = 0; tn < 2; ++tn)
                bfr[tn] = *(const bf16x8*)(myBs + buf * 2048 + (tn * 2 + ks) * 512 + lane * 8);
#pragma unroll
            for (int tm = 0; tm < 2; ++tm) {
                const u32 byte = (w[tm][ks] >> (quad * 8)) & 0xFFu;
                if (tm == 0) cnt0 += (u32)__popc(byte); else cnt1 += (u32)__popc(byte);
                const bf16x8 af = expand8(byte);
#pragma unroll
                for (int tn = 0; tn < 2; ++tn)
                    acc[tm][tn] = __builtin_amdgcn_mfma_f32_16x16x32_bf16(
                        af, bfr[tn], acc[tm][tn], 0, 0, 0);
            }
        }
    };

    STAGE(0, 0);
    LOADW(0, wA);
    for (int i = 0; i < 8; ++i) {
        STAGE(2 * i + 1, 1);
        LOADW(2 * i + 1, wB);
        COMPUTE(0, wA);                          // iter 2i (buf 0)
        const int nxt = (2 * i + 2 < 16) ? (2 * i + 2) : 15;   // tail: harmless re-stage
        STAGE(nxt, 0);
        LOADW(nxt, wA);
        COMPUTE(1, wB);                          // iter 2i+1 (buf 1)
    }

    // de partials: lanes l, l+16, l+32, l+48 hold the 4 quad-bytes of edge row16
    cnt0 += __shfl_down(cnt0, 32, 64); cnt0 += __shfl_down(cnt0, 16, 64);
    cnt1 += __shfl_down(cnt1, 32, 64); cnt1 += __shfl_down(cnt1, 16, 64);
    if (lane < 16) {
        cnts[wv][0][lane] = (float)cnt0;
        cnts[wv][1][lane] = (float)cnt1;
    }
    __syncthreads();                 // all staging dead -> overlay reduce buffer
    {
        float* redf = (float*)smem;  // [(wv*64+lane)*17 + j], stride 17: conflict-free
        float* my = &redf[(size_t)(wv * 64 + lane) * 17];
#pragma unroll
        for (int tm = 0; tm < 2; ++tm)
#pragma unroll
            for (int tn = 0; tn < 2; ++tn)
#pragma unroll
                for (int r = 0; r < 4; ++r)
                    my[tm * 8 + tn * 4 + r] = acc[tm][tn][r];
    }
    __syncthreads();
    {
        const float* redf = (const float*)smem;
#pragma unroll
        for (int h = 0; h < 2; ++h) {
            const int idx = tid + h * 512;       // flat [32 e][32 f]
            const int el = idx >> 5, fl = idx & 31;
            const int tm = el >> 4, q = (el >> 2) & 3, r = el & 3;
            const int tn = fl >> 4, r16 = fl & 15;
            const int srcl = q * 16 + r16;
            const int j = tm * 8 + tn * 4 + r;
            float s = 0.f, de = 0.f;
#pragma unroll
            for (int w = 0; w < 8; ++w) {
                s += redf[(size_t)(w * 64 + srcl) * 17 + j];
                de += cnts[w][tm][el & 15];
            }
            Mb[(size_t)(e0 + el) * F_DIM + f0 + fl] = f2bf(s / de);
        }
    }
}

// ---------------------------------------------------------------------------
// spmm2w — fused node-aggregate + output GEMM. (R7 structure — passed 4x.)
//   Y[n][:]  = sum_{e in n} Mb[e][:]            (fp32, Mb 512 KB L2-resident)
//   Yb[n][:] = bf16( rsqrt(dv[n]) * Y[n][:] )   (LDS)
//   out[n][j] = sum_f Yb[n][f]*Wb[j][f] + b[j]  (MFMA, Wb pre-converted bf16)
// 1024 blocks x 512 thr, one wave per node -> 32 waves/CU.
// ---------------------------------------------------------------------------
__global__ __launch_bounds__(512) void spmm2w(
    const u16* __restrict__ Mb, const float* __restrict__ dv,
    const u16* __restrict__ nlist, const u16* __restrict__ Wb,
    const float* __restrict__ bias, float* __restrict__ out) {
    __shared__ u16 nl[8 * NMAX];           // 2 KB
    __shared__ u16 Yb[8][264];             // 4.1 KB
    const int tid = threadIdx.x;
    const int wv = tid >> 6;               // node slot 0..7
    const int lane = tid & 63;
    const int n0 = blockIdx.x * 8;
    ((u32*)nl)[tid] = ((const u32*)&nlist[(size_t)n0 * NMAX])[tid];
    __syncthreads();
    const int half = lane >> 5, l32 = lane & 31;
    const int n = n0 + wv;
    const float dvn = dv[n];
    const int cnt = min((int)dvn, NMAX);
    const u16* lt = &nl[wv * NMAX];
    float a[8] = {};
    const int npairs = (cnt + 1) >> 1;
#pragma unroll 8
    for (int p = 0; p < npairs; ++p) {
        const int idx0 = 2 * p + half;
        const int idx = min(idx0, cnt - 1);
        const float msk = (idx0 < cnt) ? 1.f : 0.f;
        const int e = lt[idx];
        const u32x4 pk = *(const u32x4*)(&Mb[(size_t)e * F_DIM + l32 * 8]);
        a[0] = fmaf(bflo(pk[0]), msk, a[0]); a[1] = fmaf(bfhi(pk[0]), msk, a[1]);
        a[2] = fmaf(bflo(pk[1]), msk, a[2]); a[3] = fmaf(bfhi(pk[1]), msk, a[3]);
        a[4] = fmaf(bflo(pk[2]), msk, a[4]); a[5] = fmaf(bfhi(pk[2]), msk, a[5]);
        a[6] = fmaf(bflo(pk[3]), msk, a[6]); a[7] = fmaf(bfhi(pk[3]), msk, a[7]);
    }
#pragma unroll
    for (int k = 0; k < 8; ++k) a[k] += __shfl_xor(a[k], 32, 64);
    const float s = rsqrtf(dvn);
    if (half == 0) {                       // lanes 0..31 write the row
        u32x4 pk;
        pk[0] = (u32)f2bf(a[0] * s) | ((u32)f2bf(a[1] * s) << 16);
        pk[1] = (u32)f2bf(a[2] * s) | ((u32)f2bf(a[3] * s) << 16);
        pk[2] = (u32)f2bf(a[4] * s) | ((u32)f2bf(a[5] * s) << 16);
        pk[3] = (u32)f2bf(a[6] * s) | ((u32)f2bf(a[7] * s) << 16);
        *(u32x4*)(&Yb[wv][l32 * 8]) = pk;
    }
    __syncthreads();
    // ---- phase B: out[8 x 256] = Yb @ Wb^T + b; wave wv owns 32 cols ----
    const int row16 = lane & 15, quad = lane >> 4;
    f32x4 acc[2] = {};
    for (int ko = 0; ko < 256; ko += 32) {
        bf16x8 af = {};
        if (row16 < 8)
            af = *(const bf16x8*)(&Yb[row16][ko + quad * 8]);
#pragma unroll
        for (int tn = 0; tn < 2; ++tn) {
            const int j = wv * 32 + tn * 16 + row16;
            const bf16x8 bf = *(const bf16x8*)(&Wb[(size_t)j * F_DIM + ko + quad * 8]);
            acc[tn] = __builtin_amdgcn_mfma_f32_16x16x32_bf16(af, bf, acc[tn], 0, 0, 0);
        }
    }
#pragma unroll
    for (int tn = 0; tn < 2; ++tn) {
        const int col = wv * 32 + tn * 16 + row16;
        const float bc = bias[col];
#pragma unroll
        for (int r2 = 0; r2 < 4; ++r2) {
            const int row = quad * 4 + r2;
            if (row < 8)
                out[(size_t)(n0 + row) * F_DIM + col] = acc[tn][r2] + bc;
        }
    }
}

// ---------------------------------------------------------------------------
extern "C" void kernel_launch(void* const* d_in, const int* in_sizes, int n_in,
                              void* d_out, int out_size, void* d_ws, size_t ws_size,
                              hipStream_t stream) {
    (void)in_sizes; (void)n_in; (void)out_size; (void)ws_size;
    const float* X = (const float*)d_in[0];   // [8192 x 256]
    const float* H = (const float*)d_in[1];   // [8192 x 1024]
    const float* W = (const float*)d_in[2];   // [256 x 256]
    const float* b = (const float*)d_in[3];   // [256]
    float* out = (float*)d_out;               // [8192 x 256] fp32

    char* ws = (char*)d_ws;
    float* dv    = (float*)(ws);               // 32 KB  [8192]
    u32*   HbTs  = (u32*)(ws + 0x10000);       // 1 MB   [256 seg][1024 e] u32
    u16*   nlist = (u16*)(ws + 0x110000);      // 2 MB   [8192][128]
    u16*   Xst   = (u16*)(ws + 0x310000);      // 4 MB   [256 f][8192 n] bf16
    u16*   Mb    = (u16*)(ws + 0x710000);      // 512 KB [1024][256] bf16 (has /de)
    u16*   Wb    = (u16*)(ws + 0x790000);      // 128 KB [256][256] bf16

    prep<<<256, 512, 0, stream>>>(H, X, W, dv, nlist, Xst, HbTs, Wb);
    gemm1<<<256, 512, 0, stream>>>(Xst, HbTs, Mb);
    spmm2w<<<N_NODES / 8, 512, 0, stream>>>(Mb, dv, nlist, Wb, b, out);
}

// Round 12
// 121.820 us; speedup vs baseline: 1.4378x; 1.1364x over previous
//
#include <hip/hip_runtime.h>
#include <hip/hip_bf16.h>
#include <stdint.h>

typedef __attribute__((ext_vector_type(8))) short bf16x8;
typedef __attribute__((ext_vector_type(4))) float f32x4;
typedef __attribute__((ext_vector_type(4))) unsigned int u32x4;
typedef __attribute__((ext_vector_type(2))) unsigned int u32x2;
typedef unsigned short u16;
typedef unsigned int u32;
typedef unsigned char u8;
typedef unsigned long long u64;

#define N_NODES 8192
#define N_EDGES 1024
#define F_DIM   256

__device__ __forceinline__ u16 f2bf(float f) {
    union { float f; u32 u; } v; v.f = f;
    u32 u = v.u;
    u = (u + 0x7FFFu + ((u >> 16) & 1u)) >> 16;   // round-nearest-even
    return (u16)u;
}

// async 16B global -> LDS (wave-uniform LDS base + lane*16; per-lane global src)
__device__ __forceinline__ void async16(const u16* g, u16* l) {
    __builtin_amdgcn_global_load_lds(
        (const __attribute__((address_space(1))) u32*)(const void*)g,
        (__attribute__((address_space(3))) u32*)(void*)l, 16, 0, 0);
}

// expand 8 mask bits -> bf16x8 of {1.0, 0.0} (elem j = bit j)
__device__ __forceinline__ bf16x8 expand8(u32 byte) {
    union { u32 u[4]; bf16x8 v; } r;
#pragma unroll
    for (int i = 0; i < 4; ++i)
        r.u[i] = (((byte >> (2 * i)) & 1u) ? 0x3F80u : 0u)
               | (((byte >> (2 * i + 1)) & 1u) ? 0x3F800000u : 0u);
    return r.v;
}

// ---------------------------------------------------------------------------
// prep v4 — ONE pass over H (33.5 MB, the only cold HBM read). Block = 32
// rows, 8 waves x 4 rows. All serial machinery DELETED (no nlist scan/scatter,
// no LDS transpose): dv is a plain popcount-reduce. Produces:
//   dv[n]            row popcounts
//   Xsb[n][f]        bf16(X*rsqrt(dv)) ROW-major (gemmZ B-operand)
//   HbTs[seg][e]     node-chunk-major bitmask (gemmM2 A)
//   HbN[we][n]       edge-word-major bitmask (gemmOUT A)
//   Wb               bf16(W)
// hmask padded [32][68]: assembly reads are <=2-way (free).
// ---------------------------------------------------------------------------
__global__ __launch_bounds__(512) void prep(
    const float* __restrict__ H, const float* __restrict__ X,
    const float* __restrict__ W,
    float* __restrict__ dv, u16* __restrict__ Xsb,
    u32* __restrict__ HbTs, u32* __restrict__ HbN, u16* __restrict__ Wb) {
    __shared__ u16 hmask[32][68];     // 4.25 KB (pad 68: 2-way max on reads)
    const int tid = threadIdx.x;
    const int wv = tid >> 6;
    const int lane = tid & 63;
    const int blk = blockIdx.x;
    const int n0 = blk * 32 + wv * 4;

    f32x4 hv[4][4], xv[4];
#pragma unroll
    for (int r = 0; r < 4; ++r) {
        const int n = n0 + r;
#pragma unroll
        for (int q = 0; q < 4; ++q)
            hv[r][q] = *(const f32x4*)(&H[(size_t)n * N_EDGES + q * 256 + lane * 4]);
        xv[r] = *(const f32x4*)(&X[(size_t)n * F_DIM + lane * 4]);
    }

    // Wb: block blk converts W row blk (256 f32 -> bf16), one wave, ~free
    if (wv == 7) {
        const f32x4 w = *(const f32x4*)(&W[(size_t)blk * F_DIM + lane * 4]);
        u32x2 pk;
        pk[0] = (u32)f2bf(w[0]) | ((u32)f2bf(w[1]) << 16);
        pk[1] = (u32)f2bf(w[2]) | ((u32)f2bf(w[3]) << 16);
        *(u32x2*)(&Wb[(size_t)blk * F_DIM + lane * 4]) = pk;
    }

#pragma unroll
    for (int r = 0; r < 4; ++r) {
        const int n = n0 + r;
        u32 m16 = 0u;
#pragma unroll
        for (int q = 0; q < 4; ++q)
#pragma unroll
            for (int j = 0; j < 4; ++j)
                m16 |= ((hv[r][q][j] != 0.f) ? 1u : 0u) << (q * 4 + j);
        hmask[wv * 4 + r][lane] = (u16)m16;
        u32 s = (u32)__popc(m16);
#pragma unroll
        for (int d = 1; d < 64; d <<= 1) s += __shfl_xor(s, d, 64);
        if (lane == 0) dv[n] = (float)s;
        const float sc = rsqrtf((float)s);
        u32x2 pk;
        pk[0] = (u32)f2bf(xv[r][0] * sc) | ((u32)f2bf(xv[r][1] * sc) << 16);
        pk[1] = (u32)f2bf(xv[r][2] * sc) | ((u32)f2bf(xv[r][3] * sc) << 16);
        *(u32x2*)(&Xsb[(size_t)n * F_DIM + lane * 4]) = pk;
    }
    __syncthreads();
    // HbTs node-chunk-major: thread t -> edges 2t, 2t+1 (4 KB coalesced row)
    {
        u32x2 st;
#pragma unroll
        for (int eo = 0; eo < 2; ++eo) {
            const int e = tid * 2 + eo;
            const int widx = (e & 255) >> 2;
            const int bit = ((e >> 8) << 2) + (e & 3);
            u32 w = 0u;
#pragma unroll
            for (int r = 0; r < 32; ++r)
                w |= (u32)((hmask[r][widx] >> bit) & 1u) << r;
            st[eo] = w;
        }
        *(u32x2*)(&HbTs[(size_t)blk * N_EDGES + tid * 2]) = st;
    }
    // HbN edge-word-major: bit o of word (n, we) = H[n][we*32+o].
    // entry l0+i of hmask row contributes nibble (m16>>(q*4))&0xF at bits 4i.
    {
        const int r = tid & 31;          // node-local: coalesced stores
        const int wec = tid >> 5;        // 0..15; words wec and wec+16
#pragma unroll
        for (int wo = 0; wo < 2; ++wo) {
            const int we = wec + wo * 16;
            const int q = we >> 3, l0 = (we & 7) * 8;
            const u32x2 a = *(const u32x2*)(&hmask[r][l0]);
            const u32x2 b2 = *(const u32x2*)(&hmask[r][l0 + 4]);
            const u32 sh = q * 4;
            u32 w = ((a[0] >> sh) & 0xFu)
                  | (((a[0] >> (16 + sh)) & 0xFu) << 4)
                  | (((a[1] >> sh) & 0xFu) << 8)
                  | (((a[1] >> (16 + sh)) & 0xFu) << 12)
                  | (((b2[0] >> sh) & 0xFu) << 16)
                  | (((b2[0] >> (16 + sh)) & 0xFu) << 20)
                  | (((b2[1] >> sh) & 0xFu) << 24)
                  | (((b2[1] >> (16 + sh)) & 0xFu) << 28);
            HbN[(size_t)we * N_NODES + blk * 32 + r] = w;
        }
    }
}

// ---------------------------------------------------------------------------
// gemmZ — Zt[j][n] = bf16( sum_f Wb[j][f] * Xsb[n][f] ). R0 gemm_bt structure
// verbatim (64x64 tile, 256 thr, async16 staging, K=256): A=Wb, Bt=Xsb,
// epilogue f2bf. Grid 128x4. W applied at node level (linear commute; R5
// precedent: absmax unchanged under W-placement reorder).
// ---------------------------------------------------------------------------
__global__ __launch_bounds__(256) void gemmZ(
    const u16* __restrict__ Wb, const u16* __restrict__ Xsb,
    u16* __restrict__ Zt) {
    __shared__ __align__(16) u16 As[64 * 64];
    __shared__ __align__(16) u16 Bs[64 * 64];
    const int tid = threadIdx.x;
    const int lane = tid & 63;
    const int wave = tid >> 6;
    const int wm = wave >> 1, wn = wave & 1;
    const int row16 = lane & 15;
    const int quad = lane >> 4;
    const int row0 = blockIdx.y * 64;   // j
    const int col0 = blockIdx.x * 64;   // n
    const int srow = lane >> 3;
    const int scol = (lane & 7) * 8;
    const u16* gA0 = Wb + (size_t)(row0 + wave * 16 + srow) * F_DIM + scol;
    const u16* gB0 = Xsb + (size_t)(col0 + wave * 16 + srow) * F_DIM + scol;
    const size_t rstep8 = (size_t)8 * F_DIM;
    u16* lA0 = &As[(wave * 16) * 64];
    u16* lB0 = &Bs[(wave * 16) * 64];

    f32x4 acc[2][2] = {};
    for (int k = 0; k < 256; k += 64) {
        async16(gA0 + k, lA0);
        async16(gA0 + k + rstep8, lA0 + 8 * 64);
        async16(gB0 + k, lB0);
        async16(gB0 + k + rstep8, lB0 + 8 * 64);
        __syncthreads();
#pragma unroll
        for (int ks = 0; ks < 2; ++ks) {
            bf16x8 af[2], bfr[2];
#pragma unroll
            for (int t = 0; t < 2; ++t) {
                af[t]  = *(const bf16x8*)(&As[(wm * 32 + t * 16 + row16) * 64 + ks * 32 + quad * 8]);
                bfr[t] = *(const bf16x8*)(&Bs[(wn * 32 + t * 16 + row16) * 64 + ks * 32 + quad * 8]);
            }
#pragma unroll
            for (int tm = 0; tm < 2; tm++)
#pragma unroll
                for (int tn = 0; tn < 2; tn++)
                    acc[tm][tn] = __builtin_amdgcn_mfma_f32_16x16x32_bf16(
                        af[tm], bfr[tn], acc[tm][tn], 0, 0, 0);
        }
        __syncthreads();
    }
#pragma unroll
    for (int tm = 0; tm < 2; tm++)
#pragma unroll
        for (int tn = 0; tn < 2; tn++) {
            const int col = col0 + wn * 32 + tn * 16 + row16;
#pragma unroll
            for (int r = 0; r < 4; r++) {
                const int row = row0 + wm * 32 + tm * 16 + quad * 4 + r;
                Zt[(size_t)row * N_NODES + col] = f2bf(acc[tm][tn][r]);
            }
        }
}

// ---------------------------------------------------------------------------
// gemmM2 — M2t[j][e] = bf16( (1/de) * sum_n H[n][e] * Z[n][j] ). R11 gemm1
// VERBATIM (passed) with Xst->Zt and transposed epilogue write (el-major for
// coalescing). 256 blocks x 8 waves, wave-private async16 dbuf, counted
// vmcnt(4), in-loop popcount de, f-group==XCD.
// ---------------------------------------------------------------------------
__global__ __launch_bounds__(512) void gemmM2(
    const u16* __restrict__ Zt, const u32* __restrict__ HbTs,
    u16* __restrict__ M2t) {
    __shared__ __align__(16) u8 smem[65536];
    __shared__ float cnts[8][2][16];
    const int tid = threadIdx.x;
    const int wv = tid >> 6, lane = tid & 63;
    const int f0 = ((int)blockIdx.x & 7) * 32;   // j-group == XCD
    const int e0 = ((int)blockIdx.x >> 3) * 32;
    const int row16 = lane & 15, quad = lane >> 4;
    const int srow = lane & 15, schunk = lane >> 4;
    u16* myBs = (u16*)(smem + wv * 8192);
    const int kbase = wv * 1024;

    f32x4 acc[2][2] = {};
    u32 cnt0 = 0, cnt1 = 0;
    u32 wA[2][2], wB[2][2];

    auto STAGE = [&](int it, int buf) {
        __builtin_amdgcn_sched_barrier(0);
        const int k0 = kbase + it * 64;
#pragma unroll
        for (int tn = 0; tn < 2; ++tn)
#pragma unroll
            for (int ks = 0; ks < 2; ++ks)
                async16(Zt + (size_t)(f0 + tn * 16 + srow) * N_NODES + k0 + ks * 32 + schunk * 8,
                        myBs + buf * 2048 + (tn * 2 + ks) * 512);
    };
    auto LOADW = [&](int it, u32 (&w)[2][2]) {
        const int k0 = kbase + it * 64;
#pragma unroll
        for (int tm = 0; tm < 2; ++tm)
#pragma unroll
            for (int ks = 0; ks < 2; ++ks)
                w[tm][ks] = HbTs[(size_t)((k0 >> 5) + ks) * N_EDGES + e0 + tm * 16 + row16];
    };
    auto COMPUTE = [&](int buf, u32 (&w)[2][2]) {
        asm volatile("s_waitcnt vmcnt(4)" ::: "memory");
        __builtin_amdgcn_sched_barrier(0);
#pragma unroll
        for (int ks = 0; ks < 2; ++ks) {
            bf16x8 bfr[2];
#pragma unroll
            for (int tn = 0; tn < 2; ++tn)
                bfr[tn] = *(const bf16x8*)(myBs + buf * 2048 + (tn * 2 + ks) * 512 + lane * 8);
#pragma unroll
            for (int tm = 0; tm < 2; ++tm) {
                const u32 byte = (w[tm][ks] >> (quad * 8)) & 0xFFu;
                if (tm == 0) cnt0 += (u32)__popc(byte); else cnt1 += (u32)__popc(byte);
                const bf16x8 af = expand8(byte);
#pragma unroll
                for (int tn = 0; tn < 2; ++tn)
                    acc[tm][tn] = __builtin_amdgcn_mfma_f32_16x16x32_bf16(
                        af, bfr[tn], acc[tm][tn], 0, 0, 0);
            }
        }
    };

    STAGE(0, 0);
    LOADW(0, wA);
    for (int i = 0; i < 8; ++i) {
        STAGE(2 * i + 1, 1);
        LOADW(2 * i + 1, wB);
        COMPUTE(0, wA);
        const int nxt = (2 * i + 2 < 16) ? (2 * i + 2) : 15;
        STAGE(nxt, 0);
        LOADW(nxt, wA);
        COMPUTE(1, wB);
    }

    cnt0 += __shfl_down(cnt0, 32, 64); cnt0 += __shfl_down(cnt0, 16, 64);
    cnt1 += __shfl_down(cnt1, 32, 64); cnt1 += __shfl_down(cnt1, 16, 64);
    if (lane < 16) {
        cnts[wv][0][lane] = (float)cnt0;
        cnts[wv][1][lane] = (float)cnt1;
    }
    __syncthreads();
    {
        float* redf = (float*)smem;
        float* my = &redf[(size_t)(wv * 64 + lane) * 17];
#pragma unroll
        for (int tm = 0; tm < 2; ++tm)
#pragma unroll
            for (int tn = 0; tn < 2; ++tn)
#pragma unroll
                for (int r = 0; r < 4; ++r)
                    my[tm * 8 + tn * 4 + r] = acc[tm][tn][r];
    }
    __syncthreads();
    {
        const float* redf = (const float*)smem;
#pragma unroll
        for (int h = 0; h < 2; ++h) {
            const int idx = tid + h * 512;
            const int fl = idx >> 5, el = idx & 31;   // el-major: coalesced M2t
            const int tm = el >> 4, q = (el >> 2) & 3, r = el & 3;
            const int tn = fl >> 4, r16 = fl & 15;
            const int srcl = q * 16 + r16;
            const int j = tm * 8 + tn * 4 + r;
            float s = 0.f, de = 0.f;
#pragma unroll
            for (int w = 0; w < 8; ++w) {
                s += redf[(size_t)(w * 64 + srcl) * 17 + j];
                de += cnts[w][tm][el & 15];
            }
            M2t[(size_t)(f0 + fl) * N_EDGES + e0 + el] = f2bf(s / de);
        }
    }
}

// ---------------------------------------------------------------------------
// gemmOUT — out[n][j] = rsqrt(dv[n]) * sum_e H[n][e]*M2[e][j] + b[j] as a
// bitmask-MFMA over K=1024 edges. Block = 256n x 32j (grid 256, j==XCD);
// B (32 j-rows of M2t, 64 KB padded [32][1028]) staged ONCE via async16 —
// zero global B traffic in the K-loop; A-masks double-buffered coalesced
// u32 loads. Replaces the last gather kernel (spmm2w).
// ---------------------------------------------------------------------------
__global__ __launch_bounds__(512) void gemmOUT(
    const u16* __restrict__ M2t, const u32* __restrict__ HbN,
    const float* __restrict__ dv, const float* __restrict__ bias,
    float* __restrict__ out) {
    __shared__ __align__(16) u16 Bs[32 * 1028];   // pad 1028: b64 reads ~2-way
    const int tid = threadIdx.x;
    const int wv = tid >> 6, lane = tid & 63;
    const int row16 = lane & 15, quad = lane >> 4;
    const int j0 = ((int)blockIdx.x & 7) * 32;    // j-group == XCD
    const int ng = ((int)blockIdx.x >> 3) * 256 + wv * 32;

#pragma unroll
    for (int rr = 0; rr < 4; ++rr) {
        const int jr = wv * 4 + rr;
#pragma unroll
        for (int c = 0; c < 2; ++c)
            async16(M2t + (size_t)(j0 + jr) * N_EDGES + c * 512 + lane * 8,
                    &Bs[jr * 1028 + c * 512]);
    }
    __syncthreads();   // compiler drains vmcnt before barrier

    f32x4 acc[2][2] = {};
    u32 wA[2][2], wB[2][2];
    auto LOADW = [&](int it, u32 (&w)[2][2]) {
#pragma unroll
        for (int tm = 0; tm < 2; ++tm)
#pragma unroll
            for (int ks = 0; ks < 2; ++ks)
                w[tm][ks] = HbN[(size_t)(it * 2 + ks) * N_NODES + ng + tm * 16 + row16];
    };
    auto COMPUTE = [&](int it, u32 (&w)[2][2]) {
#pragma unroll
        for (int ks = 0; ks < 2; ++ks) {
            bf16x8 bfr[2];
#pragma unroll
            for (int tn = 0; tn < 2; ++tn) {
                const int base = (tn * 16 + row16) * 1028 + it * 64 + ks * 32 + quad * 8;
                union { u32x2 lo_hi[2]; bf16x8 v; } u;
                u.lo_hi[0] = *(const u32x2*)(&Bs[base]);
                u.lo_hi[1] = *(const u32x2*)(&Bs[base + 4]);
                bfr[tn] = u.v;
            }
#pragma unroll
            for (int tm = 0; tm < 2; ++tm) {
                const u32 byte = (w[tm][ks] >> (quad * 8)) & 0xFFu;
                const bf16x8 af = expand8(byte);
#pragma unroll
                for (int tn = 0; tn < 2; ++tn)
                    acc[tm][tn] = __builtin_amdgcn_mfma_f32_16x16x32_bf16(
                        af, bfr[tn], acc[tm][tn], 0, 0, 0);
            }
        }
    };

    LOADW(0, wA);
    for (int i = 0; i < 8; ++i) {
        LOADW(2 * i + 1, wB);
        COMPUTE(2 * i, wA);
        const int nxt = (2 * i + 2 < 16) ? (2 * i + 2) : 15;
        LOADW(nxt, wA);
        COMPUTE(2 * i + 1, wB);
    }

#pragma unroll
    for (int tm = 0; tm < 2; ++tm)
#pragma unroll
        for (int tn = 0; tn < 2; ++tn) {
            const int col = j0 + tn * 16 + row16;
            const float bc = bias[col];
#pragma unroll
            for (int r = 0; r < 4; ++r) {
                const int n = ng + tm * 16 + quad * 4 + r;
                out[(size_t)n * F_DIM + col] = acc[tm][tn][r] * rsqrtf(dv[n]) + bc;
            }
        }
}

// ---------------------------------------------------------------------------
extern "C" void kernel_launch(void* const* d_in, const int* in_sizes, int n_in,
                              void* d_out, int out_size, void* d_ws, size_t ws_size,
                              hipStream_t stream) {
    (void)in_sizes; (void)n_in; (void)out_size; (void)ws_size;
    const float* X = (const float*)d_in[0];   // [8192 x 256]
    const float* H = (const float*)d_in[1];   // [8192 x 1024]
    const float* W = (const float*)d_in[2];   // [256 x 256]
    const float* b = (const float*)d_in[3];   // [256]
    float* out = (float*)d_out;               // [8192 x 256] fp32

    char* ws = (char*)d_ws;
    float* dv   = (float*)(ws);                // 32 KB  [8192]
    u32*   HbTs = (u32*)(ws + 0x10000);        // 1 MB   [256 seg][1024 e]
    u32*   HbN  = (u32*)(ws + 0x110000);       // 1 MB   [32 we][8192 n]
    u16*   Wb   = (u16*)(ws + 0x210000);       // 128 KB [256][256] bf16
    u16*   Xsb  = (u16*)(ws + 0x230000);       // 4 MB   [8192][256] bf16
    u16*   Zt   = (u16*)(ws + 0x630000);       // 4 MB   [256 j][8192 n] bf16
    u16*   M2t  = (u16*)(ws + 0xA30000);       // 512 KB [256 j][1024 e] bf16

    prep<<<256, 512, 0, stream>>>(H, X, W, dv, Xsb, HbTs, HbN, Wb);
    gemmZ<<<dim3(128, 4), 256, 0, stream>>>(Wb, Xsb, Zt);
    gemmM2<<<256, 512, 0, stream>>>(Zt, HbTs, M2t);
    gemmOUT<<<256, 512, 0, stream>>>(M2t, HbN, dv, b, out);
}